// Round 1
// baseline (1746.348 us; speedup 1.0000x reference)
//
#include <hip/hip_runtime.h>

#define NN 100000   // nodes
#define NE 200000   // edges per etype
#define NT 3        // etypes
#define DD 128      // feature dim
#define NL 3        // layers
#define EPSV 1e-5f

// ---------------- CSR build ----------------

__global__ __launch_bounds__(256) void count_kernel(const int* __restrict__ dst,
                                                    int* __restrict__ cnt) {
  int gid = blockIdx.x * 256 + threadIdx.x;
  if (gid >= NT * NE) return;
  int et = gid / NE;
  atomicAdd(&cnt[et * NN + dst[gid]], 1);
}

// one block (1024 threads) per etype: exclusive scan of counts -> row_ptr
__global__ __launch_bounds__(1024) void scan_kernel(const int* __restrict__ cnt,
                                                    int* __restrict__ rp) {
  __shared__ int s[1024];
  __shared__ int run;
  int et = blockIdx.x;
  const int* c = cnt + et * NN;
  int* r = rp + et * (NN + 1);
  int tid = threadIdx.x;
  if (tid == 0) run = 0;
  __syncthreads();
  for (int base = 0; base < NN; base += 1024) {
    int i = base + tid;
    int v = (i < NN) ? c[i] : 0;
    int brun = run;
    s[tid] = v;
    __syncthreads();
    #pragma unroll
    for (int off = 1; off < 1024; off <<= 1) {
      int t = 0;
      if (tid >= off) t = s[tid - off];
      __syncthreads();
      if (tid >= off) s[tid] += t;
      __syncthreads();
    }
    int incl = s[tid];
    if (i < NN) r[i] = brun + incl - v;
    __syncthreads();
    if (tid == 0) run = brun + s[1023];
    __syncthreads();
  }
  if (tid == 0) r[NN] = run;
}

__global__ __launch_bounds__(256) void fill_kernel(const int* __restrict__ src,
                                                   const int* __restrict__ dst,
                                                   const int* __restrict__ rp,
                                                   int* __restrict__ cursor,
                                                   int* __restrict__ col) {
  int gid = blockIdx.x * 256 + threadIdx.x;
  if (gid >= NT * NE) return;
  int et = gid / NE;
  int d = dst[gid];
  int pos = rp[et * (NN + 1) + d] + atomicAdd(&cursor[et * NN + d], 1);
  col[et * NE + pos] = src[gid];
}

// ---------------- mean aggregation (gather over CSR) ----------------
// 32 lanes per node, float4 per lane -> 512B per source row, coalesced.
__global__ __launch_bounds__(256) void aggregate_kernel(const float* __restrict__ h,
                                                        const int* __restrict__ rp,
                                                        const int* __restrict__ col,
                                                        float* __restrict__ neigh) {
  int node = blockIdx.x * 8 + (threadIdx.x >> 5);
  if (node >= NN) return;
  int lane = threadIdx.x & 31;
  int beg = rp[node], end = rp[node + 1];
  float a0 = 0.f, a1 = 0.f, a2 = 0.f, a3 = 0.f;
  for (int e = beg; e < end; ++e) {
    const float4 v = *(const float4*)(h + (size_t)col[e] * DD + (lane << 2));
    a0 += v.x; a1 += v.y; a2 += v.z; a3 += v.w;
  }
  int deg = end - beg;
  float inv = 1.0f / (float)(deg > 1 ? deg : 1);
  float4 o = {a0 * inv, a1 * inv, a2 * inv, a3 * inv};
  *(float4*)(neigh + (size_t)node * DD + (lane << 2)) = o;
}

// ---------------- fused SAGE GEMM: out += act(A@Ws + Ng@Wn + b) ----------------
// 64 rows x 128 cols per block, 256 threads, 8x4 outputs per thread, BK=32.
template <bool ACT>
__global__ __launch_bounds__(256) void gemm_kernel(const float* __restrict__ A,
                                                   const float* __restrict__ Ng,
                                                   const float* __restrict__ Ws,
                                                   const float* __restrict__ Wn,
                                                   const float* __restrict__ bias,
                                                   float* __restrict__ out) {
  __shared__ float sA[64][32];
  __shared__ float sW[32][128];
  int tid = threadIdx.x;
  int tx = tid & 31;   // col group (4 cols each)
  int ty = tid >> 5;   // row group (8 rows each)
  int row0 = blockIdx.x * 64;

  float acc[8][4];
  #pragma unroll
  for (int i = 0; i < 8; ++i)
    #pragma unroll
    for (int j = 0; j < 4; ++j) acc[i][j] = 0.f;

  for (int pass = 0; pass < 2; ++pass) {
    const float* Ap = pass ? Ng : A;
    const float* Wp = pass ? Wn : Ws;
    for (int k0 = 0; k0 < DD; k0 += 32) {
      __syncthreads();  // protect LDS reuse
      {
        int lr = tid >> 3;
        int lc = (tid & 7) << 2;
        int gr = row0 + lr;
        float4 z = {0.f, 0.f, 0.f, 0.f};
        float4 v0 = (gr < NN) ? *(const float4*)(Ap + (size_t)gr * DD + k0 + lc) : z;
        float4 v1 = (gr + 32 < NN) ? *(const float4*)(Ap + (size_t)(gr + 32) * DD + k0 + lc) : z;
        *(float4*)&sA[lr][lc] = v0;
        *(float4*)&sA[lr + 32][lc] = v1;
      }
      {
        int wc = (tid & 31) << 2;
        int wr = tid >> 5;  // 0..7
        #pragma unroll
        for (int rr = 0; rr < 32; rr += 8)
          *(float4*)&sW[wr + rr][wc] = *(const float4*)(Wp + (size_t)(k0 + wr + rr) * DD + wc);
      }
      __syncthreads();
      #pragma unroll
      for (int k = 0; k < 32; ++k) {
        float4 wv = *(float4*)&sW[k][tx << 2];
        #pragma unroll
        for (int rr = 0; rr < 8; ++rr) {
          float a = sA[ty * 8 + rr][k];
          acc[rr][0] += a * wv.x;
          acc[rr][1] += a * wv.y;
          acc[rr][2] += a * wv.z;
          acc[rr][3] += a * wv.w;
        }
      }
    }
  }

  float4 bv = *(const float4*)(bias + (tx << 2));
  #pragma unroll
  for (int rr = 0; rr < 8; ++rr) {
    int row = row0 + ty * 8 + rr;
    if (row < NN) {
      float ox = acc[rr][0] + bv.x;
      float oy = acc[rr][1] + bv.y;
      float oz = acc[rr][2] + bv.z;
      float ow = acc[rr][3] + bv.w;
      if (ACT) {
        ox = fmaxf(ox, 0.f); oy = fmaxf(oy, 0.f);
        oz = fmaxf(oz, 0.f); ow = fmaxf(ow, 0.f);
      }
      float4* p = (float4*)(out + (size_t)row * DD + (tx << 2));
      float4 c = *p;
      c.x += ox; c.y += oy; c.z += oz; c.w += ow;
      *p = c;
    }
  }
}

// ---------------- batchnorm ----------------

__global__ __launch_bounds__(128) void bn_stats_kernel(const float* __restrict__ h,
                                                       float* __restrict__ sums) {
  int c = threadIdx.x;  // 128 columns
  float s = 0.f, s2 = 0.f;
  for (int r = blockIdx.x; r < NN; r += gridDim.x) {
    float v = h[(size_t)r * DD + c];
    s += v;
    s2 += v * v;
  }
  atomicAdd(&sums[c], s);
  atomicAdd(&sums[DD + c], s2);
}

__global__ __launch_bounds__(128) void bn_finalize_kernel(const float* __restrict__ sums,
                                                          const float* __restrict__ gamma,
                                                          const float* __restrict__ beta,
                                                          float* __restrict__ ss) {
  int c = threadIdx.x;
  float mean = sums[c] * (1.0f / NN);
  float var = sums[DD + c] * (1.0f / NN) - mean * mean;
  float sc = gamma[c] * rsqrtf(var + EPSV);
  ss[c] = sc;
  ss[DD + c] = beta[c] - mean * sc;
}

__global__ __launch_bounds__(256) void bn_apply_kernel(float* __restrict__ h,
                                                       const float* __restrict__ ss) {
  const int total = NN * DD / 4;
  for (int i = blockIdx.x * 256 + threadIdx.x; i < total; i += gridDim.x * 256) {
    int c4 = (i & 31) << 2;  // column of this float4 (D/4 == 32)
    float4 v = ((float4*)h)[i];
    float4 sc = *(const float4*)&ss[c4];
    float4 sh = *(const float4*)&ss[DD + c4];
    v.x = v.x * sc.x + sh.x;
    v.y = v.y * sc.y + sh.y;
    v.z = v.z * sc.z + sh.z;
    v.w = v.w * sc.w + sh.w;
    ((float4*)h)[i] = v;
  }
}

// ---------------- launch ----------------

static inline size_t align_up(size_t x, size_t a) { return (x + a - 1) & ~(a - 1); }

extern "C" void kernel_launch(void* const* d_in, const int* in_sizes, int n_in,
                              void* d_out, int out_size, void* d_ws, size_t ws_size,
                              hipStream_t stream) {
  const float* feat    = (const float*)d_in[0];
  const int*   src     = (const int*)d_in[1];
  const int*   dst     = (const int*)d_in[2];
  const float* W_self  = (const float*)d_in[3];
  const float* W_neigh = (const float*)d_in[4];
  const float* b       = (const float*)d_in[5];
  const float* gamma   = (const float*)d_in[6];
  const float* beta    = (const float*)d_in[7];
  float* out = (float*)d_out;

  char* w = (char*)d_ws;
  size_t off = 0;
  float* bufA = (float*)(w + off);  off = align_up(off + (size_t)NN * DD * 4, 256);
  float* neigh = (float*)(w + off); off = align_up(off + (size_t)NN * DD * 4, 256);
  int* rp = (int*)(w + off);        off = align_up(off + (size_t)NT * (NN + 1) * 4, 256);
  int* col = (int*)(w + off);       off = align_up(off + (size_t)NT * NE * 4, 256);
  int* cnt = (int*)(w + off);       off = align_up(off + (size_t)NT * NN * 4, 256);
  float* sums = (float*)(w + off);  off = align_up(off + 256 * 4, 256);
  float* ss = (float*)(w + off);    off = align_up(off + 256 * 4, 256);

  // ---- CSR build (reused by all layers) ----
  hipMemsetAsync(cnt, 0, (size_t)NT * NN * 4, stream);
  count_kernel<<<(NT * NE + 255) / 256, 256, 0, stream>>>(dst, cnt);
  scan_kernel<<<NT, 1024, 0, stream>>>(cnt, rp);
  hipMemsetAsync(cnt, 0, (size_t)NT * NN * 4, stream);
  fill_kernel<<<(NT * NE + 255) / 256, 256, 0, stream>>>(src, dst, rp, cnt, col);

  const float* cur = feat;
  for (int l = 0; l < NL; ++l) {
    float* next = (l == 1) ? bufA : out;
    hipMemsetAsync(next, 0, (size_t)NN * DD * 4, stream);
    for (int e = 0; e < NT; ++e) {
      aggregate_kernel<<<(NN + 7) / 8, 256, 0, stream>>>(cur, rp + e * (NN + 1),
                                                         col + e * NE, neigh);
      const float* Wsp = W_self + ((size_t)l * NT + e) * DD * DD;
      const float* Wnp = W_neigh + ((size_t)l * NT + e) * DD * DD;
      const float* bb  = b + ((size_t)l * NT + e) * DD;
      if (l < NL - 1)
        gemm_kernel<true><<<(NN + 63) / 64, 256, 0, stream>>>(cur, neigh, Wsp, Wnp, bb, next);
      else
        gemm_kernel<false><<<(NN + 63) / 64, 256, 0, stream>>>(cur, neigh, Wsp, Wnp, bb, next);
    }
    hipMemsetAsync(sums, 0, 256 * 4, stream);
    bn_stats_kernel<<<2048, 128, 0, stream>>>(next, sums);
    bn_finalize_kernel<<<1, 128, 0, stream>>>(sums, gamma + l * DD, beta + l * DD, ss);
    bn_apply_kernel<<<2048, 256, 0, stream>>>(next, ss);
    cur = next;
  }
}

// Round 2
// 1299.621 us; speedup vs baseline: 1.3437x; 1.3437x over previous
//
#include <hip/hip_runtime.h>

#define NN 100000   // nodes
#define NE 200000   // edges per etype
#define NT 3        // etypes
#define DD 128      // feature dim
#define NL 3        // layers
#define EPSV 1e-5f
#define SCB 98      // ceil(NN / 1024) scan chunks per etype

typedef __attribute__((ext_vector_type(8))) short short8;
typedef __attribute__((ext_vector_type(4))) float f32x4;

__device__ __forceinline__ float bf2f(unsigned short u) {
  unsigned v = ((unsigned)u) << 16;
  return __builtin_bit_cast(float, v);
}
__device__ __forceinline__ unsigned short f2bf(float f) {
  unsigned u = __builtin_bit_cast(unsigned, f);
  u += 0x7FFF + ((u >> 16) & 1);  // round-to-nearest-even
  return (unsigned short)(u >> 16);
}

// ---------------- CSR build ----------------

__global__ __launch_bounds__(256) void count_kernel(const int* __restrict__ dst,
                                                    int* __restrict__ cnt) {
  int gid = blockIdx.x * 256 + threadIdx.x;
  if (gid >= NT * NE) return;
  int et = gid / NE;
  atomicAdd(&cnt[et * NN + dst[gid]], 1);
}

// phase A: per-chunk (1024 elems) exclusive scan written to rp; chunk totals to aux
__global__ __launch_bounds__(256) void scanA(const int* __restrict__ cnt,
                                             int* __restrict__ rp,
                                             int* __restrict__ aux) {
  __shared__ int sm[256];
  int et = blockIdx.x / SCB, ch = blockIdx.x % SCB;
  const int* c = cnt + et * NN;
  int* r = rp + et * (NN + 1);
  int t = threadIdx.x;
  int base = ch * 1024;
  int v[4];
  int s = 0;
  #pragma unroll
  for (int j = 0; j < 4; ++j) {
    int i = base + t * 4 + j;
    v[j] = (i < NN) ? c[i] : 0;
    s += v[j];
  }
  sm[t] = s;
  __syncthreads();
  #pragma unroll
  for (int off = 1; off < 256; off <<= 1) {
    int x = 0;
    if (t >= off) x = sm[t - off];
    __syncthreads();
    if (t >= off) sm[t] += x;
    __syncthreads();
  }
  int run = sm[t] - s;  // exclusive prefix of this thread's 4 elems
  if (t == 255) aux[et * SCB + ch] = sm[255];
  #pragma unroll
  for (int j = 0; j < 4; ++j) {
    int i = base + t * 4 + j;
    if (i < NN) r[i] = run;
    run += v[j];
  }
}

// phase B: exclusive scan of chunk totals (serial per etype; 98 adds each) + rp[NN]
__global__ __launch_bounds__(64) void scanB(int* __restrict__ aux, int* __restrict__ rp) {
  int et = threadIdx.x;
  if (et >= NT) return;
  int run = 0;
  for (int ch = 0; ch < SCB; ++ch) {
    int x = aux[et * SCB + ch];
    aux[et * SCB + ch] = run;
    run += x;
  }
  rp[et * (NN + 1) + NN] = run;
}

// phase C: add chunk offsets
__global__ __launch_bounds__(256) void scanC(int* __restrict__ rp, const int* __restrict__ aux) {
  int et = blockIdx.x / SCB, ch = blockIdx.x % SCB;
  int off = aux[et * SCB + ch];
  int* r = rp + et * (NN + 1);
  int base = ch * 1024 + threadIdx.x * 4;
  #pragma unroll
  for (int j = 0; j < 4; ++j) {
    int i = base + j;
    if (i < NN) r[i] += off;
  }
}

__global__ __launch_bounds__(256) void fill_kernel(const int* __restrict__ src,
                                                   const int* __restrict__ dst,
                                                   const int* __restrict__ rp,
                                                   int* __restrict__ cursor,
                                                   int* __restrict__ col) {
  int gid = blockIdx.x * 256 + threadIdx.x;
  if (gid >= NT * NE) return;
  int et = gid / NE;
  int d = dst[gid];
  int pos = rp[et * (NN + 1) + d] + atomicAdd(&cursor[et * NN + d], 1);
  col[et * NE + pos] = src[gid];
}

// ---------------- conversions ----------------

__global__ __launch_bounds__(256) void convert_f2b(const float* __restrict__ x,
                                                   unsigned short* __restrict__ y) {
  const int n4 = NN * DD / 4;
  for (int i = blockIdx.x * 256 + threadIdx.x; i < n4; i += gridDim.x * 256) {
    float4 v = ((const float4*)x)[i];
    ushort4 o = make_ushort4(f2bf(v.x), f2bf(v.y), f2bf(v.z), f2bf(v.w));
    ((ushort4*)y)[i] = o;
  }
}

// all 18 weight matrices fp32 [K][N] -> bf16 transposed [N][K]
// wt layout index m = (l*NT+e)*2 + which(0=self,1=neigh)
__global__ __launch_bounds__(256) void convert_wt(const float* __restrict__ Ws,
                                                  const float* __restrict__ Wn,
                                                  unsigned short* __restrict__ wt) {
  int gid = blockIdx.x * 256 + threadIdx.x;
  if (gid >= 2 * NL * NT * DD * DD) return;
  int k = gid & 127, n = (gid >> 7) & 127, m = gid >> 14;
  const float* W = (m & 1) ? Wn : Ws;
  int le = m >> 1;
  wt[gid] = f2bf(W[((size_t)le << 14) + (k << 7) + n]);
}

// ---------------- mean aggregation (bf16 gather over CSR) ----------------

__global__ __launch_bounds__(256) void aggregate_bf(const unsigned short* __restrict__ h,
                                                    const int* __restrict__ rp,
                                                    const int* __restrict__ col,
                                                    unsigned short* __restrict__ ng) {
  int node = blockIdx.x * 8 + (threadIdx.x >> 5);
  if (node >= NN) return;
  int lane = threadIdx.x & 31;
  int beg = rp[node], end = rp[node + 1];
  float a0 = 0.f, a1 = 0.f, a2 = 0.f, a3 = 0.f;
  for (int e = beg; e < end; ++e) {
    ushort4 v = *(const ushort4*)(h + (size_t)col[e] * DD + lane * 4);
    a0 += bf2f(v.x); a1 += bf2f(v.y); a2 += bf2f(v.z); a3 += bf2f(v.w);
  }
  int deg = end - beg;
  float inv = 1.0f / (float)(deg > 1 ? deg : 1);
  ushort4 o = make_ushort4(f2bf(a0 * inv), f2bf(a1 * inv), f2bf(a2 * inv), f2bf(a3 * inv));
  *(ushort4*)(ng + (size_t)node * DD + lane * 4) = o;
}

// ---------------- MFMA SAGE GEMM ----------------
// P[tile] (+)= relu(h@Ws + ng@Wn + b)   per etype; FIRST etype writes, others RMW.
// 128x128 tile, 8 waves, mfma_f32_16x16x32_bf16.
// A-tiles in LDS with XOR 16B-slot swizzle (2-way conflicts only); B-frags from
// global bf16 Wt[n][k] (L1-resident, shared across waves).

template <bool FIRST, bool ACT>
__global__ __launch_bounds__(512, 4) void gemm_sage(const unsigned short* __restrict__ hbf,
                                                    const unsigned short* __restrict__ ngbf,
                                                    const unsigned short* __restrict__ wts,
                                                    const unsigned short* __restrict__ wtn,
                                                    const float* __restrict__ bias,
                                                    float* __restrict__ P) {
  __shared__ unsigned short smem[2 * 128 * 128];  // 64 KB exactly
  unsigned short* sH = smem;
  unsigned short* sN = smem + 128 * 128;
  int tid = threadIdx.x;
  int row0 = blockIdx.x * 128;

  // stage h-tile and neigh-tile (coalesced, swizzled 16B slots)
  {
    int r = tid >> 4, cs = tid & 15;
    #pragma unroll
    for (int it = 0; it < 4; ++it) {
      int row = it * 32 + r;
      int grow = row0 + row;
      int sw = (cs ^ (row & 7)) << 3;  // ushort offset of swizzled 16B slot
      uint4 vh = make_uint4(0, 0, 0, 0), vn = make_uint4(0, 0, 0, 0);
      if (grow < NN) {
        vh = *(const uint4*)(hbf + (size_t)grow * DD + cs * 8);
        vn = *(const uint4*)(ngbf + (size_t)grow * DD + cs * 8);
      }
      *(uint4*)(sH + row * DD + sw) = vh;
      *(uint4*)(sN + row * DD + sw) = vn;
    }
  }
  __syncthreads();

  int lane = tid & 63, wv = tid >> 6;
  int ln15 = lane & 15, kg = lane >> 4;  // k-group 0..3
  int lk = kg * 8;
  int arow = wv * 16 + ln15;
  int arx = arow & 7;
  const unsigned short* aH = sH + arow * DD;
  const unsigned short* aN = sN + arow * DD;

  f32x4 acc[8];
  #pragma unroll
  for (int c = 0; c < 8; ++c) acc[c] = (f32x4){0.f, 0.f, 0.f, 0.f};

  #pragma unroll
  for (int ks = 0; ks < 4; ++ks) {  // self pass: h @ Ws
    int slot = ks * 4 + kg;
    short8 a = *(const short8*)(aH + ((slot ^ arx) << 3));
    #pragma unroll
    for (int c = 0; c < 8; ++c) {
      short8 b = *(const short8*)(wts + (size_t)(c * 16 + ln15) * DD + ks * 32 + lk);
      acc[c] = __builtin_amdgcn_mfma_f32_16x16x32_bf16(a, b, acc[c], 0, 0, 0);
    }
  }
  #pragma unroll
  for (int ks = 0; ks < 4; ++ks) {  // neigh pass: ng @ Wn
    int slot = ks * 4 + kg;
    short8 a = *(const short8*)(aN + ((slot ^ arx) << 3));
    #pragma unroll
    for (int c = 0; c < 8; ++c) {
      short8 b = *(const short8*)(wtn + (size_t)(c * 16 + ln15) * DD + ks * 32 + lk);
      acc[c] = __builtin_amdgcn_mfma_f32_16x16x32_bf16(a, b, acc[c], 0, 0, 0);
    }
  }

  // bias + relu (per etype, before summation across etypes)
  #pragma unroll
  for (int c = 0; c < 8; ++c) {
    float bv = bias[c * 16 + ln15];
    #pragma unroll
    for (int r = 0; r < 4; ++r) {
      float v = acc[c][r] + bv;
      if (ACT) v = fmaxf(v, 0.f);
      acc[c][r] = v;
    }
  }

  __syncthreads();  // done reading sH/sN; reuse LDS as fp32 [128][128] scratch
  float* scr = (float*)smem;

  if (!FIRST) {  // stage current P tile (coalesced)
    #pragma unroll
    for (int it = 0; it < 8; ++it) {
      int row = it * 16 + (tid >> 5);
      int c4 = (tid & 31) * 4;
      int grow = row0 + row;
      f32x4 v = (f32x4){0.f, 0.f, 0.f, 0.f};
      if (grow < NN) v = *(const f32x4*)(P + (size_t)grow * DD + c4);
      *(f32x4*)(scr + row * DD + c4) = v;
    }
    __syncthreads();
  }

  // scatter accumulator fragments into scratch (C/D layout: col=lane&15, row=(lane>>4)*4+reg)
  int drow = wv * 16 + kg * 4;
  #pragma unroll
  for (int c = 0; c < 8; ++c) {
    int colx = c * 16 + ln15;
    #pragma unroll
    for (int r = 0; r < 4; ++r) {
      if (FIRST) scr[(drow + r) * DD + colx] = acc[c][r];
      else       scr[(drow + r) * DD + colx] += acc[c][r];
    }
  }
  __syncthreads();

  // coalesced write-out
  #pragma unroll
  for (int it = 0; it < 8; ++it) {
    int row = it * 16 + (tid >> 5);
    int c4 = (tid & 31) * 4;
    int grow = row0 + row;
    if (grow < NN)
      *(f32x4*)(P + (size_t)grow * DD + c4) = *(const f32x4*)(scr + row * DD + c4);
  }
}

// ---------------- batchnorm ----------------

__global__ __launch_bounds__(128) void bn_stats_kernel(const float* __restrict__ h,
                                                       float* __restrict__ sums) {
  int c = threadIdx.x;
  float s = 0.f, s2 = 0.f;
  for (int r = blockIdx.x; r < NN; r += gridDim.x) {
    float v = h[(size_t)r * DD + c];
    s += v;
    s2 += v * v;
  }
  atomicAdd(&sums[c], s);
  atomicAdd(&sums[DD + c], s2);
}

__global__ __launch_bounds__(128) void bn_finalize_kernel(const float* __restrict__ sums,
                                                          const float* __restrict__ gamma,
                                                          const float* __restrict__ beta,
                                                          float* __restrict__ ss) {
  int c = threadIdx.x;
  float mean = sums[c] * (1.0f / NN);
  float var = sums[DD + c] * (1.0f / NN) - mean * mean;
  float sc = gamma[c] * rsqrtf(var + EPSV);
  ss[c] = sc;
  ss[DD + c] = beta[c] - mean * sc;
}

// apply BN; write bf16 h for next layer, or fp32 final output (in place over P ok)
template <bool LASTL>
__global__ __launch_bounds__(256) void bn_apply(const float* __restrict__ P,
                                                const float* __restrict__ ss,
                                                unsigned short* __restrict__ hb,
                                                float* __restrict__ outp) {
  const int n4 = NN * DD / 4;
  for (int i = blockIdx.x * 256 + threadIdx.x; i < n4; i += gridDim.x * 256) {
    int c4 = (i & 31) << 2;
    float4 v = ((const float4*)P)[i];
    float4 sc = *(const float4*)(ss + c4);
    float4 sh = *(const float4*)(ss + DD + c4);
    v.x = v.x * sc.x + sh.x;
    v.y = v.y * sc.y + sh.y;
    v.z = v.z * sc.z + sh.z;
    v.w = v.w * sc.w + sh.w;
    if (LASTL) {
      ((float4*)outp)[i] = v;
    } else {
      ushort4 o = make_ushort4(f2bf(v.x), f2bf(v.y), f2bf(v.z), f2bf(v.w));
      ((ushort4*)hb)[i] = o;
    }
  }
}

// ---------------- launch ----------------

static inline size_t align_up(size_t x, size_t a) { return (x + a - 1) & ~(a - 1); }

extern "C" void kernel_launch(void* const* d_in, const int* in_sizes, int n_in,
                              void* d_out, int out_size, void* d_ws, size_t ws_size,
                              hipStream_t stream) {
  const float* feat    = (const float*)d_in[0];
  const int*   src     = (const int*)d_in[1];
  const int*   dst     = (const int*)d_in[2];
  const float* W_self  = (const float*)d_in[3];
  const float* W_neigh = (const float*)d_in[4];
  const float* b       = (const float*)d_in[5];
  const float* gamma   = (const float*)d_in[6];
  const float* beta    = (const float*)d_in[7];

  float* P = (float*)d_out;  // fp32 pre-BN accumulator lives in d_out (51.2 MB)

  char* w = (char*)d_ws;
  size_t off = 0;
  unsigned short* hbf  = (unsigned short*)(w + off); off = align_up(off + (size_t)NN * DD * 2, 256);
  unsigned short* ngbf = (unsigned short*)(w + off); off = align_up(off + (size_t)NN * DD * 2, 256);
  unsigned short* wt   = (unsigned short*)(w + off); off = align_up(off + (size_t)2 * NL * NT * DD * DD * 2, 256);
  int* rp  = (int*)(w + off); off = align_up(off + (size_t)NT * (NN + 1) * 4, 256);
  int* col = (int*)(w + off); off = align_up(off + (size_t)NT * NE * 4, 256);
  int* cnt = (int*)(w + off); off = align_up(off + (size_t)NT * NN * 4, 256);
  int* aux = (int*)(w + off); off = align_up(off + (size_t)NT * SCB * 4, 256);
  float* gsums = (float*)(w + off); off = align_up(off + 256 * 4, 256);
  float* ss    = (float*)(w + off); off = align_up(off + 256 * 4, 256);

  // ---- CSR build (reused by all layers) ----
  hipMemsetAsync(cnt, 0, (size_t)NT * NN * 4, stream);
  count_kernel<<<(NT * NE + 255) / 256, 256, 0, stream>>>(dst, cnt);
  scanA<<<NT * SCB, 256, 0, stream>>>(cnt, rp, aux);
  scanB<<<1, 64, 0, stream>>>(aux, rp);
  scanC<<<NT * SCB, 256, 0, stream>>>(rp, aux);
  hipMemsetAsync(cnt, 0, (size_t)NT * NN * 4, stream);
  fill_kernel<<<(NT * NE + 255) / 256, 256, 0, stream>>>(src, dst, rp, cnt, col);

  // ---- weight + feature conversion ----
  convert_wt<<<(2 * NL * NT * DD * DD + 255) / 256, 256, 0, stream>>>(W_self, W_neigh, wt);
  convert_f2b<<<1024, 256, 0, stream>>>(feat, hbf);

  const int gemm_grid = (NN + 127) / 128;
  for (int l = 0; l < NL; ++l) {
    bool act = (l < NL - 1);
    for (int e = 0; e < NT; ++e) {
      aggregate_bf<<<NN / 8, 256, 0, stream>>>(hbf, rp + e * (NN + 1), col + e * NE, ngbf);
      const unsigned short* wts = wt + (size_t)((l * NT + e) * 2 + 0) * DD * DD;
      const unsigned short* wtn = wt + (size_t)((l * NT + e) * 2 + 1) * DD * DD;
      const float* bb = b + (size_t)(l * NT + e) * DD;
      if (e == 0) {
        if (act) gemm_sage<true, true><<<gemm_grid, 512, 0, stream>>>(hbf, ngbf, wts, wtn, bb, P);
        else     gemm_sage<true, false><<<gemm_grid, 512, 0, stream>>>(hbf, ngbf, wts, wtn, bb, P);
      } else {
        if (act) gemm_sage<false, true><<<gemm_grid, 512, 0, stream>>>(hbf, ngbf, wts, wtn, bb, P);
        else     gemm_sage<false, false><<<gemm_grid, 512, 0, stream>>>(hbf, ngbf, wts, wtn, bb, P);
      }
    }
    hipMemsetAsync(gsums, 0, 256 * 4, stream);
    bn_stats_kernel<<<2048, 128, 0, stream>>>(P, gsums);
    bn_finalize_kernel<<<1, 128, 0, stream>>>(gsums, gamma + l * DD, beta + l * DD, ss);
    if (l == NL - 1) bn_apply<true><<<1024, 256, 0, stream>>>(P, ss, hbf, P);
    else             bn_apply<false><<<1024, 256, 0, stream>>>(P, ss, hbf, P);
  }
}

// Round 3
// 982.919 us; speedup vs baseline: 1.7767x; 1.3222x over previous
//
#include <hip/hip_runtime.h>

#define NN 100000   // nodes
#define NE 200000   // edges per etype
#define NT 3        // etypes
#define DD 128      // feature dim
#define NL 3        // layers
#define EPSV 1e-5f
#define SCB 98      // ceil(NN / 1024) scan chunks per etype
#define NB8 12500   // NN / 8 aggregate blocks per etype

typedef __attribute__((ext_vector_type(8))) short short8;
typedef __attribute__((ext_vector_type(4))) float f32x4;

__device__ __forceinline__ float bf2f(unsigned short u) {
  unsigned v = ((unsigned)u) << 16;
  return __builtin_bit_cast(float, v);
}
__device__ __forceinline__ unsigned short f2bf(float f) {
  unsigned u = __builtin_bit_cast(unsigned, f);
  u += 0x7FFF + ((u >> 16) & 1);  // round-to-nearest-even
  return (unsigned short)(u >> 16);
}

// ---------------- CSR build ----------------

__global__ __launch_bounds__(256) void count_kernel(const int* __restrict__ dst,
                                                    int* __restrict__ cnt) {
  int gid = blockIdx.x * 256 + threadIdx.x;
  if (gid >= NT * NE) return;
  int et = gid / NE;
  atomicAdd(&cnt[et * NN + dst[gid]], 1);
}

__global__ __launch_bounds__(256) void scanA(const int* __restrict__ cnt,
                                             int* __restrict__ rp,
                                             int* __restrict__ aux) {
  __shared__ int sm[256];
  int et = blockIdx.x / SCB, ch = blockIdx.x % SCB;
  const int* c = cnt + et * NN;
  int* r = rp + et * (NN + 1);
  int t = threadIdx.x;
  int base = ch * 1024;
  int v[4];
  int s = 0;
  #pragma unroll
  for (int j = 0; j < 4; ++j) {
    int i = base + t * 4 + j;
    v[j] = (i < NN) ? c[i] : 0;
    s += v[j];
  }
  sm[t] = s;
  __syncthreads();
  #pragma unroll
  for (int off = 1; off < 256; off <<= 1) {
    int x = 0;
    if (t >= off) x = sm[t - off];
    __syncthreads();
    if (t >= off) sm[t] += x;
    __syncthreads();
  }
  int run = sm[t] - s;
  if (t == 255) aux[et * SCB + ch] = sm[255];
  #pragma unroll
  for (int j = 0; j < 4; ++j) {
    int i = base + t * 4 + j;
    if (i < NN) r[i] = run;
    run += v[j];
  }
}

__global__ __launch_bounds__(64) void scanB(int* __restrict__ aux, int* __restrict__ rp) {
  int et = threadIdx.x;
  if (et >= NT) return;
  int run = 0;
  for (int ch = 0; ch < SCB; ++ch) {
    int x = aux[et * SCB + ch];
    aux[et * SCB + ch] = run;
    run += x;
  }
  rp[et * (NN + 1) + NN] = run;
}

__global__ __launch_bounds__(256) void scanC(int* __restrict__ rp, const int* __restrict__ aux) {
  int et = blockIdx.x / SCB, ch = blockIdx.x % SCB;
  int off = aux[et * SCB + ch];
  int* r = rp + et * (NN + 1);
  int base = ch * 1024 + threadIdx.x * 4;
  #pragma unroll
  for (int j = 0; j < 4; ++j) {
    int i = base + j;
    if (i < NN) r[i] += off;
  }
}

__global__ __launch_bounds__(256) void fill_kernel(const int* __restrict__ src,
                                                   const int* __restrict__ dst,
                                                   const int* __restrict__ rp,
                                                   int* __restrict__ cursor,
                                                   int* __restrict__ col) {
  int gid = blockIdx.x * 256 + threadIdx.x;
  if (gid >= NT * NE) return;
  int et = gid / NE;
  int d = dst[gid];
  int pos = rp[et * (NN + 1) + d] + atomicAdd(&cursor[et * NN + d], 1);
  col[et * NE + pos] = src[gid];
}

// ---------------- conversions ----------------

__global__ __launch_bounds__(256) void convert_f2b(const float* __restrict__ x,
                                                   unsigned short* __restrict__ y) {
  const int n4 = NN * DD / 4;
  for (int i = blockIdx.x * 256 + threadIdx.x; i < n4; i += gridDim.x * 256) {
    float4 v = ((const float4*)x)[i];
    ushort4 o = make_ushort4(f2bf(v.x), f2bf(v.y), f2bf(v.z), f2bf(v.w));
    ((ushort4*)y)[i] = o;
  }
}

// fp32 [K][N] -> bf16 transposed [N][K]; m = (l*NT+e)*2 + which(0=self,1=neigh)
__global__ __launch_bounds__(256) void convert_wt(const float* __restrict__ Ws,
                                                  const float* __restrict__ Wn,
                                                  unsigned short* __restrict__ wt) {
  int gid = blockIdx.x * 256 + threadIdx.x;
  if (gid >= 2 * NL * NT * DD * DD) return;
  int k = gid & 127, n = (gid >> 7) & 127, m = gid >> 14;
  const float* W = (m & 1) ? Wn : Ws;
  int le = m >> 1;
  wt[gid] = f2bf(W[((size_t)le << 14) + (k << 7) + n]);
}

// ---------------- mean aggregation: all etypes in one launch ----------------

__global__ __launch_bounds__(256) void aggregate_bf(const unsigned short* __restrict__ h,
                                                    const int* __restrict__ rp,
                                                    const int* __restrict__ col,
                                                    unsigned short* __restrict__ ng) {
  int et = blockIdx.x / NB8;
  int nb = blockIdx.x % NB8;
  int node = nb * 8 + (threadIdx.x >> 5);
  int lane = threadIdx.x & 31;
  const int* rpe = rp + et * (NN + 1);
  const int* ce = col + et * NE;
  unsigned short* nge = ng + (size_t)et * NN * DD;
  int beg = rpe[node], end = rpe[node + 1];
  float a0 = 0.f, a1 = 0.f, a2 = 0.f, a3 = 0.f;
  int e = beg;
  for (; e + 1 < end; e += 2) {  // two gathers in flight
    int c0 = ce[e], c1 = ce[e + 1];
    ushort4 v0 = *(const ushort4*)(h + (size_t)c0 * DD + lane * 4);
    ushort4 v1 = *(const ushort4*)(h + (size_t)c1 * DD + lane * 4);
    a0 += bf2f(v0.x) + bf2f(v1.x);
    a1 += bf2f(v0.y) + bf2f(v1.y);
    a2 += bf2f(v0.z) + bf2f(v1.z);
    a3 += bf2f(v0.w) + bf2f(v1.w);
  }
  if (e < end) {
    ushort4 v0 = *(const ushort4*)(h + (size_t)ce[e] * DD + lane * 4);
    a0 += bf2f(v0.x); a1 += bf2f(v0.y); a2 += bf2f(v0.z); a3 += bf2f(v0.w);
  }
  int deg = end - beg;
  float inv = 1.0f / (float)(deg > 1 ? deg : 1);
  ushort4 o = make_ushort4(f2bf(a0 * inv), f2bf(a1 * inv), f2bf(a2 * inv), f2bf(a3 * inv));
  *(ushort4*)(nge + (size_t)node * DD + lane * 4) = o;
}

// ---------------- fused MFMA SAGE layer ----------------
// P[tile] = sum_e act(h@Ws[e] + ng_e@Wn[e] + b[e]); BN column stats fused.
// 128x128 tile, 8 waves, mfma_f32_16x16x32_bf16, XOR-swizzled LDS A-tiles.

__device__ __forceinline__ void stage_tile(unsigned short* dst,
                                           const unsigned short* __restrict__ src,
                                           int row0, int tid) {
  int r = tid >> 4, cs = tid & 15;
  #pragma unroll
  for (int it = 0; it < 4; ++it) {
    int row = it * 32 + r;
    int grow = row0 + row;
    int sw = (cs ^ (row & 7)) << 3;
    uint4 v = make_uint4(0, 0, 0, 0);
    if (grow < NN) v = *(const uint4*)(src + (size_t)grow * DD + cs * 8);
    *(uint4*)(dst + row * DD + sw) = v;
  }
}

template <bool ACT>
__global__ __launch_bounds__(512, 4) void gemm_fused(const unsigned short* __restrict__ hbf,
                                                     const unsigned short* __restrict__ ngbf,
                                                     const unsigned short* __restrict__ wtl,
                                                     const float* __restrict__ bl,
                                                     float* __restrict__ P,
                                                     float* __restrict__ gsums) {
  __shared__ unsigned short smem[2 * 128 * 128];  // 64 KB
  unsigned short* sH = smem;
  unsigned short* sN = smem + 128 * 128;
  int tid = threadIdx.x;
  int row0 = blockIdx.x * 128;

  stage_tile(sH, hbf, row0, tid);
  stage_tile(sN, ngbf, row0, tid);
  __syncthreads();

  int lane = tid & 63, wv = tid >> 6;
  int ln15 = lane & 15, kg = lane >> 4;
  int lk = kg * 8;
  int arow = wv * 16 + ln15;
  int arx = arow & 7;
  const unsigned short* aH = sH + arow * DD;
  const unsigned short* aN = sN + arow * DD;

  f32x4 out[8];
  #pragma unroll
  for (int c = 0; c < 8; ++c) out[c] = (f32x4){0.f, 0.f, 0.f, 0.f};

  #pragma unroll 1
  for (int e = 0; e < NT; ++e) {
    const unsigned short* w0 = wtl + (size_t)(e * 2) * DD * DD;
    f32x4 acc[8];
    #pragma unroll
    for (int c = 0; c < 8; ++c) acc[c] = (f32x4){0.f, 0.f, 0.f, 0.f};

    #pragma unroll
    for (int half = 0; half < 2; ++half) {
      const unsigned short* ap = half ? aN : aH;
      const unsigned short* wp = w0 + (size_t)half * DD * DD;
      #pragma unroll
      for (int ks = 0; ks < 4; ++ks) {
        short8 a = *(const short8*)(ap + (((ks * 4 + kg) ^ arx) << 3));
        short8 bfr[8];
        #pragma unroll
        for (int c = 0; c < 8; ++c)
          bfr[c] = *(const short8*)(wp + (size_t)(c * 16 + ln15) * DD + ks * 32 + lk);
        #pragma unroll
        for (int c = 0; c < 8; ++c)
          acc[c] = __builtin_amdgcn_mfma_f32_16x16x32_bf16(a, bfr[c], acc[c], 0, 0, 0);
      }
    }

    const float* be = bl + e * DD;
    #pragma unroll
    for (int c = 0; c < 8; ++c) {
      float bv = be[c * 16 + ln15];
      #pragma unroll
      for (int r = 0; r < 4; ++r) {
        float v = acc[c][r] + bv;
        if (ACT) v = fmaxf(v, 0.f);
        out[c][r] += v;
      }
    }

    if (e < NT - 1) {
      __syncthreads();
      stage_tile(sN, ngbf + (size_t)(e + 1) * NN * DD, row0, tid);
      __syncthreads();
    }
  }

  __syncthreads();  // done with bf16 tiles; reuse LDS as fp32 scratch
  float* scr = (float*)smem;

  // scatter fragments (C/D layout: col=lane&15, row=(lane>>4)*4+reg)
  int drow = wv * 16 + kg * 4;
  #pragma unroll
  for (int c = 0; c < 8; ++c) {
    int colx = c * 16 + ln15;
    #pragma unroll
    for (int r = 0; r < 4; ++r) scr[(drow + r) * DD + colx] = out[c][r];
  }
  __syncthreads();

  // coalesced write-out + per-thread column partial sums for BN
  int ty = tid >> 5;
  int c4 = (tid & 31) * 4;
  f32x4 s = (f32x4){0.f, 0.f, 0.f, 0.f};
  f32x4 s2 = (f32x4){0.f, 0.f, 0.f, 0.f};
  #pragma unroll
  for (int it = 0; it < 8; ++it) {
    int row = it * 16 + ty;
    int grow = row0 + row;
    if (grow < NN) {
      f32x4 v = *(const f32x4*)(scr + row * DD + c4);
      *(f32x4*)(P + (size_t)grow * DD + c4) = v;
      s += v;
      s2 += v * v;
    }
  }
  __syncthreads();
  *(f32x4*)(scr + ty * DD + c4) = s;
  *(f32x4*)(scr + 16 * DD + ty * DD + c4) = s2;
  __syncthreads();
  if (tid < DD) {
    float ts = 0.f, ts2 = 0.f;
    #pragma unroll
    for (int g = 0; g < 16; ++g) {
      ts += scr[g * DD + tid];
      ts2 += scr[16 * DD + g * DD + tid];
    }
    atomicAdd(gsums + tid, ts);
    atomicAdd(gsums + DD + tid, ts2);
  }
}

// ---------------- batchnorm finalize / apply ----------------

__global__ __launch_bounds__(128) void bn_finalize_kernel(const float* __restrict__ sums,
                                                          const float* __restrict__ gamma,
                                                          const float* __restrict__ beta,
                                                          float* __restrict__ ss) {
  int c = threadIdx.x;
  float mean = sums[c] * (1.0f / NN);
  float var = sums[DD + c] * (1.0f / NN) - mean * mean;
  float sc = gamma[c] * rsqrtf(var + EPSV);
  ss[c] = sc;
  ss[DD + c] = beta[c] - mean * sc;
}

template <bool LASTL>
__global__ __launch_bounds__(256) void bn_apply(const float* __restrict__ P,
                                                const float* __restrict__ ss,
                                                unsigned short* __restrict__ hb,
                                                float* __restrict__ outp) {
  const int n4 = NN * DD / 4;
  for (int i = blockIdx.x * 256 + threadIdx.x; i < n4; i += gridDim.x * 256) {
    int c4 = (i & 31) << 2;
    float4 v = ((const float4*)P)[i];
    float4 sc = *(const float4*)(ss + c4);
    float4 sh = *(const float4*)(ss + DD + c4);
    v.x = v.x * sc.x + sh.x;
    v.y = v.y * sc.y + sh.y;
    v.z = v.z * sc.z + sh.z;
    v.w = v.w * sc.w + sh.w;
    if (LASTL) {
      ((float4*)outp)[i] = v;
    } else {
      ushort4 o = make_ushort4(f2bf(v.x), f2bf(v.y), f2bf(v.z), f2bf(v.w));
      ((ushort4*)hb)[i] = o;
    }
  }
}

// ---------------- launch ----------------

static inline size_t align_up(size_t x, size_t a) { return (x + a - 1) & ~(a - 1); }

extern "C" void kernel_launch(void* const* d_in, const int* in_sizes, int n_in,
                              void* d_out, int out_size, void* d_ws, size_t ws_size,
                              hipStream_t stream) {
  const float* feat    = (const float*)d_in[0];
  const int*   src     = (const int*)d_in[1];
  const int*   dst     = (const int*)d_in[2];
  const float* W_self  = (const float*)d_in[3];
  const float* W_neigh = (const float*)d_in[4];
  const float* b       = (const float*)d_in[5];
  const float* gamma   = (const float*)d_in[6];
  const float* beta    = (const float*)d_in[7];

  float* P = (float*)d_out;  // fp32 pre-BN accumulator in d_out

  char* w = (char*)d_ws;
  size_t off = 0;
  unsigned short* hbf = (unsigned short*)(w + off); off = align_up(off + (size_t)NN * DD * 2, 256);
  unsigned short* wt  = (unsigned short*)(w + off); off = align_up(off + (size_t)2 * NL * NT * DD * DD * 2, 256);
  int* rp  = (int*)(w + off); off = align_up(off + (size_t)NT * (NN + 1) * 4, 256);
  int* col = (int*)(w + off); off = align_up(off + (size_t)NT * NE * 4, 256);
  float* gsums = (float*)(w + off); off = align_up(off + 256 * 4, 256);
  float* ss    = (float*)(w + off); off = align_up(off + 256 * 4, 256);
  // CSR-build-only buffers alias the ng region (cnt/aux dead before first aggregate)
  size_t base2 = off;
  int* cnt = (int*)(w + base2);
  int* aux = (int*)(w + align_up(base2 + (size_t)NT * NN * 4, 256));
  unsigned short* ngbf = (unsigned short*)(w + base2);  // NT * NN * DD bf16

  // ---- CSR build ----
  hipMemsetAsync(cnt, 0, (size_t)NT * NN * 4, stream);
  count_kernel<<<(NT * NE + 255) / 256, 256, 0, stream>>>(dst, cnt);
  scanA<<<NT * SCB, 256, 0, stream>>>(cnt, rp, aux);
  scanB<<<1, 64, 0, stream>>>(aux, rp);
  scanC<<<NT * SCB, 256, 0, stream>>>(rp, aux);
  hipMemsetAsync(cnt, 0, (size_t)NT * NN * 4, stream);
  fill_kernel<<<(NT * NE + 255) / 256, 256, 0, stream>>>(src, dst, rp, cnt, col);

  // ---- conversions ----
  convert_wt<<<(2 * NL * NT * DD * DD + 255) / 256, 256, 0, stream>>>(W_self, W_neigh, wt);
  convert_f2b<<<1024, 256, 0, stream>>>(feat, hbf);

  const int gemm_grid = (NN + 127) / 128;
  for (int l = 0; l < NL; ++l) {
    bool act = (l < NL - 1);
    hipMemsetAsync(gsums, 0, 256 * 4, stream);
    aggregate_bf<<<NT * NB8, 256, 0, stream>>>(hbf, rp, col, ngbf);
    const unsigned short* wtl = wt + (size_t)l * NT * 2 * DD * DD;
    const float* bl = b + (size_t)l * NT * DD;
    if (act) gemm_fused<true><<<gemm_grid, 512, 0, stream>>>(hbf, ngbf, wtl, bl, P, gsums);
    else     gemm_fused<false><<<gemm_grid, 512, 0, stream>>>(hbf, ngbf, wtl, bl, P, gsums);
    bn_finalize_kernel<<<1, 128, 0, stream>>>(gsums, gamma + l * DD, beta + l * DD, ss);
    if (l == NL - 1) bn_apply<true><<<1024, 256, 0, stream>>>(P, ss, hbf, P);
    else             bn_apply<false><<<1024, 256, 0, stream>>>(P, ss, hbf, P);
  }
}

// Round 4
// 561.163 us; speedup vs baseline: 3.1120x; 1.7516x over previous
//
#include <hip/hip_runtime.h>

#define NN 100000   // nodes
#define NE 200000   // edges per etype
#define NT 3        // etypes
#define DD 128      // feature dim
#define NL 3        // layers
#define EPSV 1e-5f
#define SCB 98      // ceil(NN / 1024) scan chunks per etype
#define NB8 12500   // NN / 8 aggregate blocks per etype

typedef __attribute__((ext_vector_type(8))) short short8;
typedef __attribute__((ext_vector_type(4))) float f32x4;

__device__ __forceinline__ float bf2f(unsigned short u) {
  unsigned v = ((unsigned)u) << 16;
  return __builtin_bit_cast(float, v);
}
__device__ __forceinline__ unsigned short f2bf(float f) {
  unsigned u = __builtin_bit_cast(unsigned, f);
  u += 0x7FFF + ((u >> 16) & 1);  // round-to-nearest-even
  return (unsigned short)(u >> 16);
}

// ---------------- CSR build ----------------

__global__ __launch_bounds__(256) void count_kernel(const int* __restrict__ dst,
                                                    int* __restrict__ cnt) {
  int gid = blockIdx.x * 256 + threadIdx.x;
  if (gid >= NT * NE) return;
  int et = gid / NE;
  atomicAdd(&cnt[et * NN + dst[gid]], 1);
}

__global__ __launch_bounds__(256) void scanA(const int* __restrict__ cnt,
                                             int* __restrict__ rp,
                                             int* __restrict__ aux) {
  __shared__ int sm[256];
  int et = blockIdx.x / SCB, ch = blockIdx.x % SCB;
  const int* c = cnt + et * NN;
  int* r = rp + et * (NN + 1);
  int t = threadIdx.x;
  int base = ch * 1024;
  int v[4];
  int s = 0;
  #pragma unroll
  for (int j = 0; j < 4; ++j) {
    int i = base + t * 4 + j;
    v[j] = (i < NN) ? c[i] : 0;
    s += v[j];
  }
  sm[t] = s;
  __syncthreads();
  #pragma unroll
  for (int off = 1; off < 256; off <<= 1) {
    int x = 0;
    if (t >= off) x = sm[t - off];
    __syncthreads();
    if (t >= off) sm[t] += x;
    __syncthreads();
  }
  int run = sm[t] - s;
  if (t == 255) aux[et * SCB + ch] = sm[255];
  #pragma unroll
  for (int j = 0; j < 4; ++j) {
    int i = base + t * 4 + j;
    if (i < NN) r[i] = run;
    run += v[j];
  }
}

__global__ __launch_bounds__(64) void scanB(int* __restrict__ aux, int* __restrict__ rp) {
  int et = threadIdx.x;
  if (et >= NT) return;
  int run = 0;
  for (int ch = 0; ch < SCB; ++ch) {
    int x = aux[et * SCB + ch];
    aux[et * SCB + ch] = run;
    run += x;
  }
  rp[et * (NN + 1) + NN] = run;
}

__global__ __launch_bounds__(256) void scanC(int* __restrict__ rp, const int* __restrict__ aux) {
  int et = blockIdx.x / SCB, ch = blockIdx.x % SCB;
  int off = aux[et * SCB + ch];
  int* r = rp + et * (NN + 1);
  int base = ch * 1024 + threadIdx.x * 4;
  #pragma unroll
  for (int j = 0; j < 4; ++j) {
    int i = base + j;
    if (i < NN) r[i] += off;
  }
}

__global__ __launch_bounds__(256) void fill_kernel(const int* __restrict__ src,
                                                   const int* __restrict__ dst,
                                                   const int* __restrict__ rp,
                                                   int* __restrict__ cursor,
                                                   int* __restrict__ col) {
  int gid = blockIdx.x * 256 + threadIdx.x;
  if (gid >= NT * NE) return;
  int et = gid / NE;
  int d = dst[gid];
  int pos = rp[et * (NN + 1) + d] + atomicAdd(&cursor[et * NN + d], 1);
  col[et * NE + pos] = src[gid];
}

// ---------------- conversions ----------------

__global__ __launch_bounds__(256) void convert_f2b(const float* __restrict__ x,
                                                   unsigned short* __restrict__ y) {
  const int n4 = NN * DD / 4;
  for (int i = blockIdx.x * 256 + threadIdx.x; i < n4; i += gridDim.x * 256) {
    float4 v = ((const float4*)x)[i];
    ushort4 o = make_ushort4(f2bf(v.x), f2bf(v.y), f2bf(v.z), f2bf(v.w));
    ((ushort4*)y)[i] = o;
  }
}

// fp32 [K][N] -> bf16 transposed [N][K]; m = (l*NT+e)*2 + which(0=self,1=neigh)
__global__ __launch_bounds__(256) void convert_wt(const float* __restrict__ Ws,
                                                  const float* __restrict__ Wn,
                                                  unsigned short* __restrict__ wt) {
  int gid = blockIdx.x * 256 + threadIdx.x;
  if (gid >= 2 * NL * NT * DD * DD) return;
  int k = gid & 127, n = (gid >> 7) & 127, m = gid >> 14;
  const float* W = (m & 1) ? Wn : Ws;
  int le = m >> 1;
  wt[gid] = f2bf(W[((size_t)le << 14) + (k << 7) + n]);
}

// ---------------- mean aggregation: all etypes, 4-deep unrolled gather ----------------

__global__ __launch_bounds__(256) void aggregate_bf(const unsigned short* __restrict__ h,
                                                    const int* __restrict__ rp,
                                                    const int* __restrict__ col,
                                                    unsigned short* __restrict__ ng) {
  int et = blockIdx.x / NB8;
  int nb = blockIdx.x % NB8;
  int node = nb * 8 + (threadIdx.x >> 5);
  int lane = threadIdx.x & 31;
  const int* rpe = rp + et * (NN + 1);
  const int* ce = col + et * NE;
  unsigned short* nge = ng + (size_t)et * NN * DD;
  int beg = rpe[node], end = rpe[node + 1];
  float a0 = 0.f, a1 = 0.f, a2 = 0.f, a3 = 0.f;
  int e = beg;
  for (; e + 3 < end; e += 4) {  // four gathers in flight
    int c0 = ce[e], c1 = ce[e + 1], c2 = ce[e + 2], c3 = ce[e + 3];
    ushort4 v0 = *(const ushort4*)(h + (size_t)c0 * DD + lane * 4);
    ushort4 v1 = *(const ushort4*)(h + (size_t)c1 * DD + lane * 4);
    ushort4 v2 = *(const ushort4*)(h + (size_t)c2 * DD + lane * 4);
    ushort4 v3 = *(const ushort4*)(h + (size_t)c3 * DD + lane * 4);
    a0 += bf2f(v0.x) + bf2f(v1.x) + bf2f(v2.x) + bf2f(v3.x);
    a1 += bf2f(v0.y) + bf2f(v1.y) + bf2f(v2.y) + bf2f(v3.y);
    a2 += bf2f(v0.z) + bf2f(v1.z) + bf2f(v2.z) + bf2f(v3.z);
    a3 += bf2f(v0.w) + bf2f(v1.w) + bf2f(v2.w) + bf2f(v3.w);
  }
  for (; e < end; ++e) {
    ushort4 v0 = *(const ushort4*)(h + (size_t)ce[e] * DD + lane * 4);
    a0 += bf2f(v0.x); a1 += bf2f(v0.y); a2 += bf2f(v0.z); a3 += bf2f(v0.w);
  }
  int deg = end - beg;
  float inv = 1.0f / (float)(deg > 1 ? deg : 1);
  ushort4 o = make_ushort4(f2bf(a0 * inv), f2bf(a1 * inv), f2bf(a2 * inv), f2bf(a3 * inv));
  *(ushort4*)(nge + (size_t)node * DD + lane * 4) = o;
}

// ---------------- fused MFMA SAGE layer ----------------
// P = sum_e act(h@Ws[e] + ng_e@Wn[e] + b[e]); BN column stats fused.
// Weights (Ws^T|Wn^T, 64 KB) staged in LDS per etype (XOR 16B-slot swizzle);
// node fragments (h, ng) held in registers. Compute phases have NO vmem ops,
// so the HBM ng stream overlaps the self-half MFMAs without vmcnt drains.

template <bool ACT>
__global__ __launch_bounds__(512, 4) void gemm_fused(const unsigned short* __restrict__ hbf,
                                                     const unsigned short* __restrict__ ngbf,
                                                     const unsigned short* __restrict__ wtl,
                                                     const float* __restrict__ bl,
                                                     float* __restrict__ P,
                                                     float* __restrict__ gsums) {
  __shared__ unsigned short wbuf[256 * DD];  // 64 KB: rows 0-127 Ws^T, 128-255 Wn^T
  int tid = threadIdx.x;
  int lane = tid & 63, wv = tid >> 6;
  int ln15 = lane & 15, kg = lane >> 4;  // kg 0..3
  int rx = ln15 & 7;
  int row0 = blockIdx.x * 128;
  int arow = row0 + wv * 16 + ln15;          // output row this lane serves
  int crow = (arow < NN) ? arow : 0;         // clamped for safe loads

  // h fragments: 16 VGPR, loaded once (row-major, 16B per ks slot)
  const unsigned short* hrow = hbf + (size_t)crow * DD;
  short8 hf[4];
  #pragma unroll
  for (int ks = 0; ks < 4; ++ks)
    hf[ks] = *(const short8*)(hrow + ks * 32 + kg * 8);

  f32x4 out[8];

  #pragma unroll
  for (int e = 0; e < NT; ++e) {
    if (e > 0) __syncthreads();  // (A) everyone done reading previous weights
    {  // stage Ws^T|Wn^T for etype e: 256 rows, 8 waves x 32 rows, swizzled ds_write
      const unsigned short* wsrc = wtl + (size_t)e * 2 * DD * DD;
      #pragma unroll
      for (int i = 0; i < 8; ++i) {
        int r = wv * 32 + i * 4 + (lane >> 4);  // 0..255
        int s = lane & 15;
        uint4 v = *(const uint4*)(wsrc + (size_t)r * DD + s * 8);
        *(uint4*)(&wbuf[r * DD + ((s ^ (r & 7)) << 3)]) = v;
      }
    }
    __syncthreads();  // (B) weights visible (vmcnt/lgkm drained; ng not yet issued)

    // bias -> accumulator init
    const float* be = bl + e * DD;
    f32x4 acc[8];
    #pragma unroll
    for (int c = 0; c < 8; ++c) {
      float bv = be[c * 16 + ln15];
      acc[c] = (f32x4){bv, bv, bv, bv};
    }

    // issue ng fragment loads now; consumed only in the neigh half below
    const unsigned short* ngrow = ngbf + (size_t)e * NN * DD + (size_t)crow * DD;
    short8 nf[4];
    #pragma unroll
    for (int ks = 0; ks < 4; ++ks)
      nf[ks] = *(const short8*)(ngrow + ks * 32 + kg * 8);

    // self half: h @ Ws_e  (weights via swizzled ds_read_b128)
    #pragma unroll
    for (int ks = 0; ks < 4; ++ks) {
      int so = ((ks * 4 + kg) ^ rx) << 3;
      #pragma unroll
      for (int c = 0; c < 8; ++c) {
        short8 bfr = *(const short8*)(&wbuf[(c * 16 + ln15) * DD + so]);
        acc[c] = __builtin_amdgcn_mfma_f32_16x16x32_bf16(hf[ks], bfr, acc[c], 0, 0, 0);
      }
    }
    // neigh half: ng_e @ Wn_e
    #pragma unroll
    for (int ks = 0; ks < 4; ++ks) {
      int so = ((ks * 4 + kg) ^ rx) << 3;
      #pragma unroll
      for (int c = 0; c < 8; ++c) {
        short8 bfr = *(const short8*)(&wbuf[(128 + c * 16 + ln15) * DD + so]);
        acc[c] = __builtin_amdgcn_mfma_f32_16x16x32_bf16(nf[ks], bfr, acc[c], 0, 0, 0);
      }
    }

    // per-etype activation, merge into out
    #pragma unroll
    for (int c = 0; c < 8; ++c) {
      #pragma unroll
      for (int r = 0; r < 4; ++r) {
        float v = acc[c][r];
        if (ACT) v = fmaxf(v, 0.f);
        out[c][r] = (e == 0) ? v : (out[c][r] + v);
      }
    }
  }

  __syncthreads();  // done with weights; reuse LDS as fp32 [128][128] scratch
  float* scr = (float*)wbuf;

  // scatter fragments (C/D layout: col=lane&15, row=(lane>>4)*4+reg)
  int drow = wv * 16 + kg * 4;
  #pragma unroll
  for (int c = 0; c < 8; ++c) {
    int colx = c * 16 + ln15;
    #pragma unroll
    for (int r = 0; r < 4; ++r) scr[(drow + r) * DD + colx] = out[c][r];
  }
  __syncthreads();

  // coalesced write-out + per-thread column partial sums for BN
  int ty = tid >> 5;
  int c4 = (tid & 31) * 4;
  f32x4 s = (f32x4){0.f, 0.f, 0.f, 0.f};
  f32x4 s2 = (f32x4){0.f, 0.f, 0.f, 0.f};
  #pragma unroll
  for (int it = 0; it < 8; ++it) {
    int row = it * 16 + ty;
    int grow = row0 + row;
    if (grow < NN) {
      f32x4 v = *(const f32x4*)(scr + row * DD + c4);
      *(f32x4*)(P + (size_t)grow * DD + c4) = v;
      s += v;
      s2 += v * v;
    }
  }
  __syncthreads();
  *(f32x4*)(scr + ty * DD + c4) = s;
  *(f32x4*)(scr + 16 * DD + ty * DD + c4) = s2;
  __syncthreads();
  if (tid < DD) {
    float ts = 0.f, ts2 = 0.f;
    #pragma unroll
    for (int g = 0; g < 16; ++g) {
      ts += scr[g * DD + tid];
      ts2 += scr[16 * DD + g * DD + tid];
    }
    atomicAdd(gsums + tid, ts);
    atomicAdd(gsums + DD + tid, ts2);
  }
}

// ---------------- batchnorm finalize / apply ----------------

__global__ __launch_bounds__(128) void bn_finalize_kernel(const float* __restrict__ sums,
                                                          const float* __restrict__ gamma,
                                                          const float* __restrict__ beta,
                                                          float* __restrict__ ss) {
  int c = threadIdx.x;
  float mean = sums[c] * (1.0f / NN);
  float var = sums[DD + c] * (1.0f / NN) - mean * mean;
  float sc = gamma[c] * rsqrtf(var + EPSV);
  ss[c] = sc;
  ss[DD + c] = beta[c] - mean * sc;
}

template <bool LASTL>
__global__ __launch_bounds__(256) void bn_apply(const float* __restrict__ P,
                                                const float* __restrict__ ss,
                                                unsigned short* __restrict__ hb,
                                                float* __restrict__ outp) {
  const int n4 = NN * DD / 4;
  for (int i = blockIdx.x * 256 + threadIdx.x; i < n4; i += gridDim.x * 256) {
    int c4 = (i & 31) << 2;
    float4 v = ((const float4*)P)[i];
    float4 sc = *(const float4*)(ss + c4);
    float4 sh = *(const float4*)(ss + DD + c4);
    v.x = v.x * sc.x + sh.x;
    v.y = v.y * sc.y + sh.y;
    v.z = v.z * sc.z + sh.z;
    v.w = v.w * sc.w + sh.w;
    if (LASTL) {
      ((float4*)outp)[i] = v;
    } else {
      ushort4 o = make_ushort4(f2bf(v.x), f2bf(v.y), f2bf(v.z), f2bf(v.w));
      ((ushort4*)hb)[i] = o;
    }
  }
}

// ---------------- launch ----------------

static inline size_t align_up(size_t x, size_t a) { return (x + a - 1) & ~(a - 1); }

extern "C" void kernel_launch(void* const* d_in, const int* in_sizes, int n_in,
                              void* d_out, int out_size, void* d_ws, size_t ws_size,
                              hipStream_t stream) {
  const float* feat    = (const float*)d_in[0];
  const int*   src     = (const int*)d_in[1];
  const int*   dst     = (const int*)d_in[2];
  const float* W_self  = (const float*)d_in[3];
  const float* W_neigh = (const float*)d_in[4];
  const float* b       = (const float*)d_in[5];
  const float* gamma   = (const float*)d_in[6];
  const float* beta    = (const float*)d_in[7];

  float* P = (float*)d_out;  // fp32 pre-BN accumulator in d_out

  char* w = (char*)d_ws;
  size_t off = 0;
  unsigned short* hbf = (unsigned short*)(w + off); off = align_up(off + (size_t)NN * DD * 2, 256);
  unsigned short* wt  = (unsigned short*)(w + off); off = align_up(off + (size_t)2 * NL * NT * DD * DD * 2, 256);
  int* rp  = (int*)(w + off); off = align_up(off + (size_t)NT * (NN + 1) * 4, 256);
  int* col = (int*)(w + off); off = align_up(off + (size_t)NT * NE * 4, 256);
  float* gsums = (float*)(w + off); off = align_up(off + 256 * 4, 256);
  float* ss    = (float*)(w + off); off = align_up(off + 256 * 4, 256);
  // CSR-build-only buffers alias the ng region (cnt/aux dead before first aggregate)
  size_t base2 = off;
  int* cnt = (int*)(w + base2);
  int* aux = (int*)(w + align_up(base2 + (size_t)NT * NN * 4, 256));
  unsigned short* ngbf = (unsigned short*)(w + base2);  // NT * NN * DD bf16

  // ---- CSR build ----
  hipMemsetAsync(cnt, 0, (size_t)NT * NN * 4, stream);
  count_kernel<<<(NT * NE + 255) / 256, 256, 0, stream>>>(dst, cnt);
  scanA<<<NT * SCB, 256, 0, stream>>>(cnt, rp, aux);
  scanB<<<1, 64, 0, stream>>>(aux, rp);
  scanC<<<NT * SCB, 256, 0, stream>>>(rp, aux);
  hipMemsetAsync(cnt, 0, (size_t)NT * NN * 4, stream);
  fill_kernel<<<(NT * NE + 255) / 256, 256, 0, stream>>>(src, dst, rp, cnt, col);

  // ---- conversions ----
  convert_wt<<<(2 * NL * NT * DD * DD + 255) / 256, 256, 0, stream>>>(W_self, W_neigh, wt);
  convert_f2b<<<1024, 256, 0, stream>>>(feat, hbf);

  const int gemm_grid = (NN + 127) / 128;
  for (int l = 0; l < NL; ++l) {
    bool act = (l < NL - 1);
    hipMemsetAsync(gsums, 0, 256 * 4, stream);
    aggregate_bf<<<NT * NB8, 256, 0, stream>>>(hbf, rp, col, ngbf);
    const unsigned short* wtl = wt + (size_t)l * NT * 2 * DD * DD;
    const float* bl = b + (size_t)l * NT * DD;
    if (act) gemm_fused<true><<<gemm_grid, 512, 0, stream>>>(hbf, ngbf, wtl, bl, P, gsums);
    else     gemm_fused<false><<<gemm_grid, 512, 0, stream>>>(hbf, ngbf, wtl, bl, P, gsums);
    bn_finalize_kernel<<<1, 128, 0, stream>>>(gsums, gamma + l * DD, beta + l * DD, ss);
    if (l == NL - 1) bn_apply<true><<<1024, 256, 0, stream>>>(P, ss, hbf, P);
    else             bn_apply<false><<<1024, 256, 0, stream>>>(P, ss, hbf, P);
  }
}